// Round 1
// baseline (1057.309 us; speedup 1.0000x reference)
//
#include <hip/hip_runtime.h>

// Net_17532056502451: 5-iter matching-pursuit loss on MI355X.
// B=4, T=256 -> 1024 positions. IDIM=ODIM=80, HDIM=512.
//
// ws layout (floats):
//   0       x_res  [81920]
//   81920   y_res  [81920]
//   163840  Wt     [81920]  Wt[c*512+f] = W_enc[f*160+c]
//   245760  Wst    [81920]  Wst[f*160+o] = W_src[o*512+f]
//   327680  sq_pos [1024]
//   328704  losses [5]
//   328709  K      [1]

#define WS_XRES   0
#define WS_YRES   81920
#define WS_WT     163840
#define WS_WST    245760
#define WS_SQ     327680
#define WS_LOSS   328704
#define WS_K      328709

__global__ void k_init(const float* __restrict__ x, const float* __restrict__ y,
                       const float* __restrict__ Wenc, const float* __restrict__ Wsrc,
                       float* __restrict__ ws) {
    int i = blockIdx.x * 256 + threadIdx.x;   // grid covers exactly 81920
    ws[WS_XRES + i] = x[i];
    ws[WS_YRES + i] = y[i];
    // Wt transpose: i = f*160 + c
    int f = i / 160, c = i - f * 160;
    ws[WS_WT + c * 512 + f] = Wenc[i];
    // Wst transpose: i = o*512 + f2
    int o = i >> 9, f2 = i & 511;
    ws[WS_WST + f2 * 160 + o] = Wsrc[i];
}

__global__ void k_count(const float* __restrict__ y, float* __restrict__ ws) {
    __shared__ int red[256];
    int tid = threadIdx.x;
    int cnt = 0;
    for (int i = tid; i < 81920; i += 256) cnt += (y[i] != 0.0f) ? 1 : 0;
    red[tid] = cnt;
    __syncthreads();
    for (int s = 128; s > 0; s >>= 1) {
        if (tid < s) red[tid] += red[tid + s];
        __syncthreads();
    }
    if (tid == 0) {
        int k = red[0]; if (k < 1) k = 1;
        ws[WS_K] = (float)k;
    }
}

__global__ __launch_bounds__(256)
void k_iter(const float* __restrict__ yorig,
            const float* __restrict__ benc, const float* __restrict__ bsrc,
            float* __restrict__ ws) {
    float* xres = ws + WS_XRES;
    float* yres = ws + WS_YRES;
    const float* Wt  = ws + WS_WT;
    const float* Wst = ws + WS_WST;
    float* sqpos = ws + WS_SQ;

    __shared__ __align__(16) float Wlds[160 * 72];
    __shared__ float xr[80], yr[80], ypad[84], xele[80], simS[159], energy[81];
    __shared__ float hsel[512], xext[160], red[256];
    __shared__ float s_ny2, s_max, s_sum;
    __shared__ int s_theta, s_hind;

    const int tid = threadIdx.x;
    const int p = blockIdx.x;
    const int base = p * 80;

    if (tid < 80) { xr[tid] = xres[base + tid]; yr[tid] = yres[base + tid]; }
    __syncthreads();

    // ---- ||y||^2 ----
    red[tid] = (tid < 80) ? yr[tid] * yr[tid] : 0.0f;
    __syncthreads();
    for (int s = 128; s > 0; s >>= 1) {
        if (tid < s) red[tid] += red[tid + s];
        __syncthreads();
    }
    if (tid == 0) s_ny2 = red[0];
    __syncthreads();

    // ---- selector: cosine sim over 159 shifts ----
    if (tid < 159) {
        int s = tid;
        int ilo = (s - 79 > 0) ? s - 79 : 0;
        int ihi = (s < 79) ? s : 79;
        float dot = 0.0f, nx2 = 0.0f;
        for (int i = ilo; i <= ihi; ++i) {
            float xv = xr[i];
            dot = fmaf(xv, yr[i - s + 79], dot);
            nx2 = fmaf(xv, xv, nx2);
        }
        float denom = sqrtf(nx2) * sqrtf(s_ny2);
        simS[s] = (denom == 0.0f) ? 0.0f : dot / denom;
    }
    __syncthreads();
    if (tid == 0) {   // first-occurrence argmax (matches jnp.argmax)
        float best = simS[0]; int bi = 0;
        for (int s = 1; s < 159; ++s) { float v = simS[s]; if (v > best) { best = v; bi = s; } }
        s_theta = bi;
    }
    __syncthreads();
    const int theta = s_theta;

    // ---- y_align, softmax attention, y_att (into ypad), x_ele ----
    float yav = 0.0f;
    if (tid < 80) {
        int ix = theta + tid - 79;
        yav = (ix >= 0 && ix < 80) ? xr[ix] : 0.0f;
        red[tid] = yav * yr[tid] / 0.7f;
    }
    __syncthreads();
    if (tid == 0) {
        float m = red[0];
        for (int i = 1; i < 80; ++i) m = fmaxf(m, red[i]);
        s_max = m;
    }
    __syncthreads();
    if (tid < 80) red[tid] = expf(red[tid] - s_max);
    __syncthreads();
    if (tid == 0) {
        float su = 0.0f;
        for (int i = 0; i < 80; ++i) su += red[i];
        s_sum = su;
    }
    __syncthreads();
    if (tid < 84 && (tid < 2 || tid >= 82)) ypad[tid] = 0.0f;
    if (tid < 80) ypad[tid + 2] = yav * (red[tid] / s_sum);
    if (tid < 81) energy[tid] = 0.0f;
    __syncthreads();
    if (tid < 80) {
        int k = 79 - theta + tid;
        xele[tid] = (k >= 0 && k < 80) ? ypad[k + 2] : 0.0f;
    }

    // ---- encoder conv: energy[s] = sum_f (b_enc[f] + sum_k y_att[k] W_enc[f,k+80-s])^2 ----
    // 8 chunks of 64 filters staged in LDS (XOR-swizzled for b128 bank spread).
    for (int ch = 0; ch < 8; ++ch) {
        __syncthreads();   // prev compute done + (ch==0) phase-A LDS writes visible
        {
            const float* Wg = Wt + ch * 64;
            for (int idx = tid; idx < 160 * 64; idx += 256) {
                int c = idx >> 6, fl = idx & 63;
                int g = fl >> 2, r = fl & 3;
                Wlds[c * 72 + (((g ^ (c & 7))) << 2) + r] = Wg[c * 512 + fl];
            }
        }
        __syncthreads();
        if (tid < 216) {
            const int st = tid >> 3, ft = tid & 7;
            const int s0 = st * 3;
            const int fb = ch * 64 + ft * 8;
            const float4 b0 = *(const float4*)(benc + fb);
            const float4 b1 = *(const float4*)(benc + fb + 4);
            const float bb[8] = {b0.x, b0.y, b0.z, b0.w, b1.x, b1.y, b1.z, b1.w};
            float acc[3][8];
#pragma unroll
            for (int r = 0; r < 3; ++r)
#pragma unroll
                for (int q = 0; q < 8; ++q) acc[r][q] = bb[q];

            const int c0 = 78 - s0;
            const int ft2 = ft * 2;
            float y0v = ypad[0], y1v = ypad[1];
            for (int j = 0; j < 82; ++j) {
                const int c = c0 + j;
                const float y2v = ypad[j + 2];
                const int swz = c & 7;
                const float* rowp = Wlds + c * 72;
                const float4 wa = *(const float4*)(rowp + ((ft2 ^ swz) << 2));
                const float4 wb = *(const float4*)(rowp + (((ft2 + 1) ^ swz) << 2));
                const float w[8] = {wa.x, wa.y, wa.z, wa.w, wb.x, wb.y, wb.z, wb.w};
#pragma unroll
                for (int q = 0; q < 8; ++q) {
                    acc[0][q] = fmaf(y0v, w[q], acc[0][q]);
                    acc[1][q] = fmaf(y1v, w[q], acc[1][q]);
                    acc[2][q] = fmaf(y2v, w[q], acc[2][q]);
                }
                y0v = y1v; y1v = y2v;
            }
#pragma unroll
            for (int r = 0; r < 3; ++r) {
                float e = 0.0f;
#pragma unroll
                for (int q = 0; q < 8; ++q) e = fmaf(acc[r][q], acc[r][q], e);
                atomicAdd(&energy[s0 + r], e);
            }
        }
    }
    __syncthreads();
    if (tid == 0) {   // first-occurrence argmax over 81 energies
        float best = energy[0]; int bi = 0;
        for (int s = 1; s < 81; ++s) { float v = energy[s]; if (v > best) { best = v; bi = s; } }
        s_hind = bi;
    }
    __syncthreads();
    const int hind = s_hind;

    // ---- recompute h_sel = h[hind, :] (coalesced over f) ----
    {
        const int cb = 80 - hind;
        int f = tid;
#pragma unroll
        for (int rep = 0; rep < 2; ++rep, f += 256) {
            float a = benc[f];
            for (int k = 0; k < 80; ++k)
                a = fmaf(ypad[k + 2], Wt[(cb + k) * 512 + f], a);
            hsel[f] = a;
        }
    }
    __syncthreads();

    // ---- decoder: x_ext[o] = b_src[o] + sum_f h_sel[f] * W_src[o,f] ----
    if (tid < 160) {
        float a0 = bsrc[tid], a1 = 0.0f, a2 = 0.0f, a3 = 0.0f;
        const float* W = Wst + tid;
        for (int f = 0; f < 512; f += 4) {
            a0 = fmaf(hsel[f],     W[f * 160],        a0);
            a1 = fmaf(hsel[f + 1], W[(f + 1) * 160],  a1);
            a2 = fmaf(hsel[f + 2], W[(f + 2) * 160],  a2);
            a3 = fmaf(hsel[f + 3], W[(f + 3) * 160],  a3);
        }
        xext[tid] = (a0 + a1) + (a2 + a3);
    }
    __syncthreads();

    // ---- loss contribution + residual update ----
    float sq = 0.0f;
    if (tid < 80) {
        float yele = xext[80 - hind + tid];
        float keep = (yorig[base + tid] != 0.0f) ? 1.0f : 0.0f;
        float d = yele - yr[tid];
        sq = d * d * keep;
        yres[base + tid] = yr[tid] - yele;
        xres[base + tid] = xr[tid] - xele[tid];
    }
    red[tid] = sq;
    __syncthreads();
    for (int s = 128; s > 0; s >>= 1) {
        if (tid < s) red[tid] += red[tid + s];
        __syncthreads();
    }
    if (tid == 0) sqpos[p] = red[0];
}

__global__ void k_fin(float* __restrict__ ws, int iter) {
    __shared__ float red[256];
    const int tid = threadIdx.x;
    const float* sqpos = ws + WS_SQ;
    float s = 0.0f;
    for (int i = tid; i < 1024; i += 256) s += sqpos[i];
    red[tid] = s;
    __syncthreads();
    for (int st = 128; st > 0; st >>= 1) {
        if (tid < st) red[tid] += red[tid + st];
        __syncthreads();
    }
    if (tid == 0) ws[WS_LOSS + iter] = red[0] / ws[WS_K];
}

__global__ void k_final(const float* __restrict__ ws, float* __restrict__ out) {
    out[0] = (ws[WS_LOSS] + ws[WS_LOSS + 1] + ws[WS_LOSS + 2] +
              ws[WS_LOSS + 3] + ws[WS_LOSS + 4]) / 5.0f;
}

extern "C" void kernel_launch(void* const* d_in, const int* in_sizes, int n_in,
                              void* d_out, int out_size, void* d_ws, size_t ws_size,
                              hipStream_t stream) {
    const float* x    = (const float*)d_in[0];
    const float* y    = (const float*)d_in[1];
    const float* Wenc = (const float*)d_in[2];
    const float* benc = (const float*)d_in[3];
    const float* Wsrc = (const float*)d_in[4];
    const float* bsrc = (const float*)d_in[5];
    float* ws  = (float*)d_ws;
    float* out = (float*)d_out;

    k_init<<<320, 256, 0, stream>>>(x, y, Wenc, Wsrc, ws);
    k_count<<<1, 256, 0, stream>>>(y, ws);
    for (int it = 0; it < 5; ++it) {
        k_iter<<<1024, 256, 0, stream>>>(y, benc, bsrc, ws);
        k_fin<<<1, 256, 0, stream>>>(ws, it);
    }
    k_final<<<1, 1, 0, stream>>>(ws, out);
}

// Round 2
// 888.936 us; speedup vs baseline: 1.1894x; 1.1894x over previous
//
#include <hip/hip_runtime.h>

// Net_17532056502451: 5-iter matching-pursuit loss on MI355X.
// B=4, T=256 -> 1024 positions, 4 positions per block -> 256 blocks (1/CU).
//
// ws layout (floats):
//   0       x_res  [81920]
//   81920   y_res  [81920]
//   163840  Wt     [81920]  Wt[c*512+f] = W_enc[f*160+c]
//   245760  Wst    [81920]  Wst[f*160+o] = W_src[o*512+f]
//   327680  sq_blk [256]
//   328704  losses [5]
//   328709  K      [1]

#define WS_XRES   0
#define WS_YRES   81920
#define WS_WT     163840
#define WS_WST    245760
#define WS_SQ     327680
#define WS_LOSS   328704
#define WS_K      328709

__global__ void k_init(const float* __restrict__ x, const float* __restrict__ y,
                       const float* __restrict__ Wenc, const float* __restrict__ Wsrc,
                       float* __restrict__ ws) {
    int i = blockIdx.x * 256 + threadIdx.x;   // grid covers exactly 81920
    ws[WS_XRES + i] = x[i];
    ws[WS_YRES + i] = y[i];
    int f = i / 160, c = i - f * 160;
    ws[WS_WT + c * 512 + f] = Wenc[i];
    int o = i >> 9, f2 = i & 511;
    ws[WS_WST + f2 * 160 + o] = Wsrc[i];
}

__global__ void k_count(const float* __restrict__ y, float* __restrict__ ws) {
    __shared__ int red[256];
    int tid = threadIdx.x;
    int cnt = 0;
    for (int i = tid; i < 81920; i += 256) cnt += (y[i] != 0.0f) ? 1 : 0;
    red[tid] = cnt;
    __syncthreads();
    for (int s = 128; s > 0; s >>= 1) {
        if (tid < s) red[tid] += red[tid + s];
        __syncthreads();
    }
    if (tid == 0) {
        int k = red[0]; if (k < 1) k = 1;
        ws[WS_K] = (float)k;
    }
}

__device__ __forceinline__ float wave_sum(float v) {
    for (int d = 32; d > 0; d >>= 1) v += __shfl_down(v, d);
    return __shfl(v, 0);
}
__device__ __forceinline__ float wave_max(float v) {
    for (int d = 32; d > 0; d >>= 1) v = fmaxf(v, __shfl_down(v, d));
    return __shfl(v, 0);
}
// first-occurrence argmax: strict >, tie -> smaller index
__device__ __forceinline__ int wave_argmax(float v, int i) {
    for (int d = 32; d > 0; d >>= 1) {
        float v2 = __shfl_down(v, d);
        int   i2 = __shfl_down(i, d);
        if (v2 > v || (v2 == v && i2 < i)) { v = v2; i = i2; }
    }
    return __shfl(i, 0);
}

__global__ __launch_bounds__(256, 1)
void k_iter(const float* __restrict__ yorig,
            const float* __restrict__ benc, const float* __restrict__ bsrc,
            float* __restrict__ ws) {
    float* xres = ws + WS_XRES;
    float* yres = ws + WS_YRES;
    const float* Wt  = ws + WS_WT;
    const float* Wst = ws + WS_WST;

    __shared__ __align__(16) float Wlds[160 * 72];   // 46 KB; overlaid by hsel/xext later
    __shared__ float xr[320], yr[320], xele[320];
    __shared__ float ypad[4][88];
    __shared__ float simS[4 * 160];
    __shared__ float energy[4][84];
    __shared__ float sbenc[512];
    __shared__ float s_ny2[4], s_sq[4];
    __shared__ int   s_hind[4];

    const int tid  = threadIdx.x;
    const int lane = tid & 63;
    const int wv   = tid >> 6;          // position index within block
    const int base = blockIdx.x * 320;  // 4 positions * 80

    for (int i = tid; i < 320; i += 256) { xr[i] = xres[base + i]; yr[i] = yres[base + i]; }
    sbenc[tid] = benc[tid];
    sbenc[tid + 256] = benc[tid + 256];
    __syncthreads();

    // ---- ||y||^2 per position (wave wv handles position wv) ----
    {
        float a = yr[wv * 80 + lane];
        float v = a * a;
        if (lane < 16) { float u = yr[wv * 80 + 64 + lane]; v = fmaf(u, u, v); }
        v = wave_sum(v);
        if (lane == 0) s_ny2[wv] = v;
    }
    __syncthreads();

    // ---- cosine sim over 159 shifts x 4 positions ----
    for (int t = tid; t < 636; t += 256) {
        int pp = t / 159, s = t - pp * 159;
        int ilo = (s - 79 > 0) ? s - 79 : 0;
        int ihi = (s < 79) ? s : 79;
        const float* xp = xr + pp * 80;
        const float* yp = yr + pp * 80;
        float dot = 0.0f, nx2 = 0.0f;
        for (int i = ilo; i <= ihi; ++i) {
            float xv = xp[i];
            dot = fmaf(xv, yp[i - s + 79], dot);
            nx2 = fmaf(xv, xv, nx2);
        }
        float denom = sqrtf(nx2) * sqrtf(s_ny2[pp]);
        simS[pp * 160 + s] = (denom == 0.0f) ? 0.0f : dot / denom;
    }
    __syncthreads();

    // ---- theta argmax + softmax attention + y_att (ypad) per wave ----
    int theta;
    {
        float v = simS[wv * 160 + lane]; int i = lane;
        { float v2 = simS[wv * 160 + lane + 64]; int i2 = lane + 64;
          if (v2 > v || (v2 == v && i2 < i)) { v = v2; i = i2; } }
        if (lane < 31) {
            float v2 = simS[wv * 160 + lane + 128]; int i2 = lane + 128;
            if (v2 > v || (v2 == v && i2 < i)) { v = v2; i = i2; }
        }
        theta = wave_argmax(v, i);
    }
    {
        const float* xp = xr + wv * 80;
        const float* yp = yr + wv * 80;
        int t0 = lane, t1 = lane + 64;
        int ix0 = theta + t0 - 79;
        float ya0 = (ix0 >= 0 && ix0 < 80) ? xp[ix0] : 0.0f;
        float z0 = ya0 * yp[t0] / 0.7f;
        float ya1 = 0.0f, z1 = -INFINITY;
        if (t1 < 80) {
            int ix1 = theta + t1 - 79;
            ya1 = (ix1 >= 0 && ix1 < 80) ? xp[ix1] : 0.0f;
            z1 = ya1 * yp[t1] / 0.7f;
        }
        float m = wave_max(fmaxf(z0, z1));
        float e0 = expf(z0 - m);
        float e1 = (t1 < 80) ? expf(z1 - m) : 0.0f;
        float S = wave_sum(e0 + e1);
        ypad[wv][2 + t0] = ya0 * (e0 / S);
        if (t1 < 80) ypad[wv][2 + t1] = ya1 * (e1 / S);
        if (lane < 2) ypad[wv][lane] = 0.0f;
        if (lane < 6) ypad[wv][82 + lane] = 0.0f;
    }
    __syncthreads();
    // ---- x_ele per wave (reads own ypad, barrier above makes it safe) ----
    {
        int t0 = lane, t1 = lane + 64;
        int k0 = 79 - theta + t0;
        xele[wv * 80 + t0] = (k0 >= 0 && k0 < 80) ? ypad[wv][k0 + 2] : 0.0f;
        if (t1 < 80) {
            int k1 = 79 - theta + t1;
            xele[wv * 80 + t1] = (k1 >= 0 && k1 < 80) ? ypad[wv][k1 + 2] : 0.0f;
        }
    }

    // ---- encoder conv: energy[p][s] = sum_f (b[f] + sum_k y_att[p][k] W[f,k+80-s])^2 ----
    const int st = tid >> 3, ft = tid & 7;   // 27 shift-tiles x 8 filter-tiles = 216 threads
    const int s0 = st * 3;
    float eacc[4][3] = {{0.f,0.f,0.f},{0.f,0.f,0.f},{0.f,0.f,0.f},{0.f,0.f,0.f}};

    for (int ch = 0; ch < 8; ++ch) {
        __syncthreads();   // prev chunk's Wlds reads complete
        {
            const float* Wg = Wt + ch * 64;
            for (int idx = tid; idx < 2560; idx += 256) {   // 160 rows x 16 float4
                int c = idx >> 4, f4 = idx & 15;
                float4 v = *(const float4*)(Wg + c * 512 + f4 * 4);
                *(float4*)(Wlds + c * 72 + ((f4 ^ (c & 7)) << 2)) = v;
            }
        }
        __syncthreads();
        if (tid < 216) {
            const int fb = ch * 64 + ft * 8;
            const float4 b0 = *(const float4*)(sbenc + fb);
            const float4 b1 = *(const float4*)(sbenc + fb + 4);
            const float bb[8] = {b0.x, b0.y, b0.z, b0.w, b1.x, b1.y, b1.z, b1.w};
            float acc[4][3][8];
#pragma unroll
            for (int p = 0; p < 4; ++p)
#pragma unroll
                for (int r = 0; r < 3; ++r)
#pragma unroll
                    for (int q = 0; q < 8; ++q) acc[p][r][q] = bb[q];

            float y0[4], y1[4], y2[4];
#pragma unroll
            for (int p = 0; p < 4; ++p) { y0[p] = ypad[p][0]; y1[p] = ypad[p][1]; }

            const int c0 = 78 - s0;
            const int ft2 = ft * 2;
#pragma unroll 3
            for (int j = 0; j < 82; ++j) {
                const int c = c0 + j;
                const int swz = c & 7;
                const float* rowp = Wlds + c * 72;
                const float4 wa = *(const float4*)(rowp + ((ft2 ^ swz) << 2));
                const float4 wb = *(const float4*)(rowp + (((ft2 + 1) ^ swz) << 2));
                const float w[8] = {wa.x, wa.y, wa.z, wa.w, wb.x, wb.y, wb.z, wb.w};
#pragma unroll
                for (int p = 0; p < 4; ++p) {
                    y2[p] = ypad[p][j + 2];
#pragma unroll
                    for (int q = 0; q < 8; ++q) {
                        acc[p][0][q] = fmaf(y0[p], w[q], acc[p][0][q]);
                        acc[p][1][q] = fmaf(y1[p], w[q], acc[p][1][q]);
                        acc[p][2][q] = fmaf(y2[p], w[q], acc[p][2][q]);
                    }
                    y0[p] = y1[p]; y1[p] = y2[p];
                }
            }
#pragma unroll
            for (int p = 0; p < 4; ++p)
#pragma unroll
                for (int r = 0; r < 3; ++r) {
                    float e = 0.0f;
#pragma unroll
                    for (int q = 0; q < 8; ++q) e = fmaf(acc[p][r][q], acc[p][r][q], e);
                    eacc[p][r] += e;
                }
        }
    }

    // ---- energy reduce over the 8 ft lanes (all lanes shuffle; guarded write) ----
#pragma unroll
    for (int p = 0; p < 4; ++p)
#pragma unroll
        for (int r = 0; r < 3; ++r) {
            float e = eacc[p][r];
            e += __shfl_down(e, 4);
            e += __shfl_down(e, 2);
            e += __shfl_down(e, 1);
            if (tid < 216 && ft == 0) energy[p][s0 + r] = e;
        }
    __syncthreads();

    // ---- h_ind argmax per wave ----
    {
        float v = energy[wv][lane]; int i = lane;
        if (lane < 17) {
            float v2 = energy[wv][lane + 64]; int i2 = lane + 64;
            if (v2 > v || (v2 == v && i2 < i)) { v = v2; i = i2; }
        }
        int hind = wave_argmax(v, i);
        if (lane == 0) s_hind[wv] = hind;
    }
    __syncthreads();

    float* hselL = Wlds;          // overlay: 4*512
    float* xextL = Wlds + 2048;   // overlay: 4*160

    // ---- recompute h_sel rows (coalesced over f) ----
    for (int t = tid; t < 2048; t += 256) {
        int pp = t >> 9, f = t & 511;
        int cb = 80 - s_hind[pp];
        const float* Wp = Wt + cb * 512 + f;
        float a = sbenc[f];
        for (int k = 0; k < 80; ++k) a = fmaf(ypad[pp][k + 2], Wp[k * 512], a);
        hselL[t] = a;
    }
    __syncthreads();

    // ---- decoder GEMV ----
    for (int t = tid; t < 640; t += 256) {
        int pp = t / 160, o = t - pp * 160;
        const float* hp = hselL + pp * 512;
        const float* W = Wst + o;
        float a0 = bsrc[o], a1 = 0.0f, a2 = 0.0f, a3 = 0.0f;
        for (int f = 0; f < 512; f += 4) {
            a0 = fmaf(hp[f],     W[f * 160],       a0);
            a1 = fmaf(hp[f + 1], W[(f + 1) * 160], a1);
            a2 = fmaf(hp[f + 2], W[(f + 2) * 160], a2);
            a3 = fmaf(hp[f + 3], W[(f + 3) * 160], a3);
        }
        xextL[t] = (a0 + a1) + (a2 + a3);
    }
    __syncthreads();

    // ---- loss + residual update per wave ----
    {
        int hd = s_hind[wv];
        int t0 = lane, t1 = lane + 64;
        float sq;
        {
            float yele = xextL[wv * 160 + 80 - hd + t0];
            float yv = yr[wv * 80 + t0];
            float keep = (yorig[base + wv * 80 + t0] != 0.0f) ? 1.0f : 0.0f;
            float d = yele - yv;
            sq = d * d * keep;
            yres[base + wv * 80 + t0] = yv - yele;
            xres[base + wv * 80 + t0] = xr[wv * 80 + t0] - xele[wv * 80 + t0];
        }
        if (t1 < 80) {
            float yele = xextL[wv * 160 + 80 - hd + t1];
            float yv = yr[wv * 80 + t1];
            float keep = (yorig[base + wv * 80 + t1] != 0.0f) ? 1.0f : 0.0f;
            float d = yele - yv;
            sq = fmaf(d * keep, d, sq);
            yres[base + wv * 80 + t1] = yv - yele;
            xres[base + wv * 80 + t1] = xr[wv * 80 + t1] - xele[wv * 80 + t1];
        }
        sq = wave_sum(sq);
        if (lane == 0) s_sq[wv] = sq;
    }
    __syncthreads();
    if (tid == 0)
        ws[WS_SQ + blockIdx.x] = (s_sq[0] + s_sq[1]) + (s_sq[2] + s_sq[3]);
}

__global__ void k_fin(float* __restrict__ ws, int iter) {
    __shared__ float red[256];
    const int tid = threadIdx.x;
    red[tid] = ws[WS_SQ + tid];
    __syncthreads();
    for (int st = 128; st > 0; st >>= 1) {
        if (tid < st) red[tid] += red[tid + st];
        __syncthreads();
    }
    if (tid == 0) ws[WS_LOSS + iter] = red[0] / ws[WS_K];
}

__global__ void k_final(const float* __restrict__ ws, float* __restrict__ out) {
    out[0] = (ws[WS_LOSS] + ws[WS_LOSS + 1] + ws[WS_LOSS + 2] +
              ws[WS_LOSS + 3] + ws[WS_LOSS + 4]) / 5.0f;
}

extern "C" void kernel_launch(void* const* d_in, const int* in_sizes, int n_in,
                              void* d_out, int out_size, void* d_ws, size_t ws_size,
                              hipStream_t stream) {
    const float* x    = (const float*)d_in[0];
    const float* y    = (const float*)d_in[1];
    const float* Wenc = (const float*)d_in[2];
    const float* benc = (const float*)d_in[3];
    const float* Wsrc = (const float*)d_in[4];
    const float* bsrc = (const float*)d_in[5];
    float* ws  = (float*)d_ws;
    float* out = (float*)d_out;

    k_init<<<320, 256, 0, stream>>>(x, y, Wenc, Wsrc, ws);
    k_count<<<1, 256, 0, stream>>>(y, ws);
    for (int it = 0; it < 5; ++it) {
        k_iter<<<256, 256, 0, stream>>>(y, benc, bsrc, ws);
        k_fin<<<1, 256, 0, stream>>>(ws, it);
    }
    k_final<<<1, 1, 0, stream>>>(ws, out);
}